// Round 2
// baseline (255.427 us; speedup 1.0000x reference)
//
#include <hip/hip_runtime.h>
#include <hip/hip_bf16.h>
#include <stdint.h>

// B=16, S=512, D=512, H=8, DH=64. Float tensors are fp32; mask int32; out fp32.
// Internally: bf16 for all MFMA operands, fp32 accumulation.

typedef __hip_bfloat16 bf16;
typedef __bf16 bf16x8 __attribute__((ext_vector_type(8)));
typedef float f32x4 __attribute__((ext_vector_type(4)));

#define MFMA16(a, b, c) __builtin_amdgcn_mfma_f32_16x16x32_bf16((a), (b), (c), 0, 0, 0)

static __device__ __forceinline__ bf16 f2b(float v) { return __float2bfloat16(v); }
static __device__ __forceinline__ bf16x8 ld8(const bf16* p) { return *(const bf16x8*)p; }

// ---------------------------------------------------------------- transpose + cast
// WT[n][k] = (bf16)W[k][n], 512x512. blockIdx.z selects which weight.
__global__ __launch_bounds__(256) void transpose512(
    const float* __restrict__ W0, const float* __restrict__ W1,
    const float* __restrict__ W2, const float* __restrict__ W3,
    bf16* __restrict__ T0, bf16* __restrict__ T1,
    bf16* __restrict__ T2, bf16* __restrict__ T3) {
  __shared__ float t[32][33];
  const float* src; bf16* dst;
  switch (blockIdx.z) {
    case 0: src = W0; dst = T0; break;
    case 1: src = W1; dst = T1; break;
    case 2: src = W2; dst = T2; break;
    default: src = W3; dst = T3; break;
  }
  int tx = threadIdx.x, ty = threadIdx.y;           // 32 x 8
  int n0 = blockIdx.x * 32, k0 = blockIdx.y * 32;
#pragma unroll
  for (int i = 0; i < 4; i++) {
    int kk = ty * 4 + i;
    t[kk][tx] = src[(k0 + kk) * 512 + n0 + tx];
  }
  __syncthreads();
#pragma unroll
  for (int i = 0; i < 4; i++) {
    int nn = ty * 4 + i;
    dst[(n0 + nn) * 512 + k0 + tx] = f2b(t[tx][nn]);
  }
}

// ---------------------------------------------------------------- LayerNorm(x) -> h (bf16)
__global__ __launch_bounds__(256) void ln_rows(
    const float* __restrict__ x, const float* __restrict__ g,
    const float* __restrict__ be, bf16* __restrict__ h) {
  int row = blockIdx.x;
  int tid = threadIdx.x;
  const float* xr = x + (size_t)row * 512;
  float v0 = xr[tid], v1 = xr[tid + 256];
  float s = v0 + v1, s2 = v0 * v0 + v1 * v1;
#pragma unroll
  for (int m = 1; m < 64; m <<= 1) {
    s += __shfl_xor(s, m);
    s2 += __shfl_xor(s2, m);
  }
  __shared__ float rs[4], rs2[4];
  int w = tid >> 6;
  if ((tid & 63) == 0) { rs[w] = s; rs2[w] = s2; }
  __syncthreads();
  s = rs[0] + rs[1] + rs[2] + rs[3];
  s2 = rs2[0] + rs2[1] + rs2[2] + rs2[3];
  float mean = s * (1.0f / 512.0f);
  float var = s2 * (1.0f / 512.0f) - mean * mean;
  float rstd = rsqrtf(var + 1e-5f);
  bf16* hr = h + (size_t)row * 512;
  hr[tid] = f2b((v0 - mean) * rstd * g[tid] + be[tid]);
  hr[tid + 256] = f2b((v1 - mean) * rstd * g[tid + 256] + be[tid + 256]);
}

// ---------------------------------------------------------------- QKV GEMM
// C[m][n] = h[m][:] @ W[:][n] + bias ; M=8192 (b*512+s), N=512 (hh*64+dh), K=512.
// sel 0: q (scaled by 0.125) -> [B,H,S,DH]; sel 1: k -> [B,H,S,DH]; sel 2: v^T -> [B,H,DH,S].
__global__ __launch_bounds__(256) void gemm_qkv(
    const bf16* __restrict__ hm,
    const bf16* __restrict__ WT0, const bf16* __restrict__ WT1, const bf16* __restrict__ WT2,
    const float* __restrict__ bq, const float* __restrict__ bk, const float* __restrict__ bv,
    bf16* __restrict__ outq, bf16* __restrict__ outk, bf16* __restrict__ outvT) {
  const int sel = blockIdx.z;
  const bf16* WT = sel == 0 ? WT0 : (sel == 1 ? WT1 : WT2);
  const float* bias = sel == 0 ? bq : (sel == 1 ? bk : bv);
  __shared__ __align__(16) bf16 As[128][40];
  __shared__ __align__(16) bf16 Bs[128][40];
  int tid = threadIdx.x;
  int w = tid >> 6, lane = tid & 63, q4 = lane >> 4, l16 = lane & 15;
  int wr = w >> 1, wc = w & 1;
  int m0 = blockIdx.x * 128, n0 = blockIdx.y * 128;
  f32x4 acc[4][4];
#pragma unroll
  for (int i = 0; i < 4; i++)
#pragma unroll
    for (int j = 0; j < 4; j++) acc[i][j] = (f32x4){0.f, 0.f, 0.f, 0.f};

  for (int kc = 0; kc < 16; kc++) {
    int k0 = kc * 32;
#pragma unroll
    for (int u = tid; u < 512; u += 256) {
      int row = u >> 2, c8 = (u & 3) * 8;
      *(bf16x8*)&As[row][c8] = ld8(&hm[(size_t)(m0 + row) * 512 + k0 + c8]);
      *(bf16x8*)&Bs[row][c8] = ld8(&WT[(size_t)(n0 + row) * 512 + k0 + c8]);
    }
    __syncthreads();
    bf16x8 af[4], bfr[4];
#pragma unroll
    for (int rt = 0; rt < 4; rt++) af[rt] = ld8(&As[wr * 64 + rt * 16 + l16][q4 * 8]);
#pragma unroll
    for (int nt = 0; nt < 4; nt++) bfr[nt] = ld8(&Bs[wc * 64 + nt * 16 + l16][q4 * 8]);
#pragma unroll
    for (int rt = 0; rt < 4; rt++)
#pragma unroll
      for (int nt = 0; nt < 4; nt++) acc[rt][nt] = MFMA16(af[rt], bfr[nt], acc[rt][nt]);
    __syncthreads();
  }

  // epilogue: C row = m0+wr*64+rt*16+q4*4+r ; col = n0+wc*64+nt*16+l16
#pragma unroll
  for (int rt = 0; rt < 4; rt++) {
    int mbase = m0 + wr * 64 + rt * 16 + q4 * 4;
    int b = mbase >> 9, s0 = mbase & 511;
#pragma unroll
    for (int nt = 0; nt < 4; nt++) {
      int n = n0 + wc * 64 + nt * 16 + l16;
      float bsv = bias[n];
      int hh = n >> 6, dh = n & 63;
      if (sel == 2) {
        union { bf16 q[4]; uint2 u; } pk;
#pragma unroll
        for (int r = 0; r < 4; r++) pk.q[r] = f2b(acc[rt][nt][r] + bsv);
        *(uint2*)(outvT + ((size_t)((b * 8 + hh) * 64 + dh)) * 512 + s0) = pk.u;
      } else {
        bf16* dst = sel == 0 ? outq : outk;
        float scale = sel == 0 ? 0.125f : 1.0f;
#pragma unroll
        for (int r = 0; r < 4; r++)
          dst[((size_t)((b * 8 + hh) * 512 + s0 + r)) * 64 + dh] =
              f2b((acc[rt][nt][r] + bsv) * scale);
      }
    }
  }
}

// ---------------------------------------------------------------- fused attention
// Per block: one (b,h), 32 q-rows. Wave w covers keys [w*128, w*128+128).
__global__ __launch_bounds__(256) void attn_fused(
    const bf16* __restrict__ q, const bf16* __restrict__ k, const bf16* __restrict__ vT,
    const int* __restrict__ mask, const float* __restrict__ lg, const float* __restrict__ lb,
    bf16* __restrict__ ctx) {
  int m0 = blockIdx.x * 32;
  int bh = blockIdx.y;
  int b = bh >> 3, hh = bh & 7;
  int tid = threadIdx.x;
  int w = tid >> 6, lane = tid & 63, q4 = lane >> 4, l16 = lane & 15;

  __shared__ __align__(16) bf16 P[32][520];
  __shared__ float rsum[4][32], rsq[4][32], rmx[4][32];

  const bf16* qb = q + ((size_t)bh * 512 + m0) * 64;
  const bf16* kb = k + (size_t)bh * 512 * 64;

  f32x4 acc[2][8];
#pragma unroll
  for (int rt = 0; rt < 2; rt++)
#pragma unroll
    for (int nt = 0; nt < 8; nt++) acc[rt][nt] = (f32x4){0.f, 0.f, 0.f, 0.f};

  // ---- phase 1: scores = (q*0.125) @ k^T, fragments straight from global
#pragma unroll
  for (int ks = 0; ks < 2; ks++) {
    bf16x8 af0 = ld8(&qb[(size_t)(l16)*64 + ks * 32 + q4 * 8]);
    bf16x8 af1 = ld8(&qb[(size_t)(16 + l16) * 64 + ks * 32 + q4 * 8]);
#pragma unroll
    for (int nt = 0; nt < 8; nt++) {
      int key = w * 128 + nt * 16 + l16;
      bf16x8 bfr = ld8(&kb[(size_t)key * 64 + ks * 32 + q4 * 8]);
      acc[0][nt] = MFMA16(af0, bfr, acc[0][nt]);
      acc[1][nt] = MFMA16(af1, bfr, acc[1][nt]);
    }
  }

  // ---- phase 2a: row sum / sumsq (per wave partial over its 128 cols)
#pragma unroll
  for (int rt = 0; rt < 2; rt++)
#pragma unroll
    for (int r = 0; r < 4; r++) {
      float s = 0.f, s2 = 0.f;
#pragma unroll
      for (int nt = 0; nt < 8; nt++) {
        float v = acc[rt][nt][r];
        s += v;
        s2 += v * v;
      }
#pragma unroll
      for (int mm = 1; mm < 16; mm <<= 1) {
        s += __shfl_xor(s, mm);
        s2 += __shfl_xor(s2, mm);
      }
      if (l16 == 0) {
        int row = rt * 16 + q4 * 4 + r;
        rsum[w][row] = s;
        rsq[w][row] = s2;
      }
    }
  __syncthreads();

  float mean[2][4], rstd[2][4];
#pragma unroll
  for (int rt = 0; rt < 2; rt++)
#pragma unroll
    for (int r = 0; r < 4; r++) {
      int row = rt * 16 + q4 * 4 + r;
      float s = rsum[0][row] + rsum[1][row] + rsum[2][row] + rsum[3][row];
      float s2 = rsq[0][row] + rsq[1][row] + rsq[2][row] + rsq[3][row];
      float mu = s * (1.0f / 512.0f);
      float var = s2 * (1.0f / 512.0f) - mu * mu;
      mean[rt][r] = mu;
      rstd[rt][r] = rsqrtf(var + 1e-5f);
    }

  // ---- phase 2b: LN (per-col gamma/beta) + mask + row max
  float gc[8], bc[8];
#pragma unroll
  for (int nt = 0; nt < 8; nt++) {
    int col = w * 128 + nt * 16 + l16;
    gc[nt] = lg[col];
    bc[nt] = lb[col];
  }
  const int* mbase = mask + ((size_t)b * 512 + m0) * 512;
  float mx[2][4];
#pragma unroll
  for (int rt = 0; rt < 2; rt++)
#pragma unroll
    for (int r = 0; r < 4; r++) mx[rt][r] = -3.0e38f;
#pragma unroll
  for (int rt = 0; rt < 2; rt++)
#pragma unroll
    for (int nt = 0; nt < 8; nt++)
#pragma unroll
      for (int r = 0; r < 4; r++) {
        int rowl = rt * 16 + q4 * 4 + r;
        float v = (acc[rt][nt][r] - mean[rt][r]) * rstd[rt][r] * gc[nt] + bc[nt];
        int mv = mbase[(size_t)rowl * 512 + w * 128 + nt * 16 + l16];
        v = (mv == 0) ? -1.0e9f : v;
        acc[rt][nt][r] = v;
        mx[rt][r] = fmaxf(mx[rt][r], v);
      }
#pragma unroll
  for (int rt = 0; rt < 2; rt++)
#pragma unroll
    for (int r = 0; r < 4; r++) {
#pragma unroll
      for (int mm = 1; mm < 16; mm <<= 1) mx[rt][r] = fmaxf(mx[rt][r], __shfl_xor(mx[rt][r], mm));
      if (l16 == 0) rmx[w][rt * 16 + q4 * 4 + r] = mx[rt][r];
    }
  __syncthreads();

  float gm[2][4];
#pragma unroll
  for (int rt = 0; rt < 2; rt++)
#pragma unroll
    for (int r = 0; r < 4; r++) {
      int row = rt * 16 + q4 * 4 + r;
      gm[rt][r] = fmaxf(fmaxf(rmx[0][row], rmx[1][row]), fmaxf(rmx[2][row], rmx[3][row]));
    }

  // ---- phase 2c: exp + row sum
#pragma unroll
  for (int rt = 0; rt < 2; rt++)
#pragma unroll
    for (int r = 0; r < 4; r++) {
      float se = 0.f;
#pragma unroll
      for (int nt = 0; nt < 8; nt++) {
        float p = __expf(acc[rt][nt][r] - gm[rt][r]);
        acc[rt][nt][r] = p;
        se += p;
      }
#pragma unroll
      for (int mm = 1; mm < 16; mm <<= 1) se += __shfl_xor(se, mm);
      if (l16 == 0) rsum[w][rt * 16 + q4 * 4 + r] = se;  // safe reuse (sync above)
    }
  __syncthreads();

  float inv[2][4];
#pragma unroll
  for (int rt = 0; rt < 2; rt++)
#pragma unroll
    for (int r = 0; r < 4; r++) {
      int row = rt * 16 + q4 * 4 + r;
      inv[rt][r] = 1.0f / (rsum[0][row] + rsum[1][row] + rsum[2][row] + rsum[3][row]);
    }

  // ---- write probabilities (bf16) to LDS in A-operand-friendly layout
#pragma unroll
  for (int rt = 0; rt < 2; rt++)
#pragma unroll
    for (int nt = 0; nt < 8; nt++)
#pragma unroll
      for (int r = 0; r < 4; r++)
        P[rt * 16 + q4 * 4 + r][w * 128 + nt * 16 + l16] = f2b(acc[rt][nt][r] * inv[rt][r]);
  __syncthreads();

  // ---- phase 3: out = P @ v ; wave w handles dh in [w*16, w*16+16)
  f32x4 o[2];
  o[0] = (f32x4){0.f, 0.f, 0.f, 0.f};
  o[1] = (f32x4){0.f, 0.f, 0.f, 0.f};
  const bf16* vb = vT + ((size_t)bh * 64 + w * 16) * 512;
#pragma unroll
  for (int ks = 0; ks < 16; ks++) {
    bf16x8 bv8 = ld8(&vb[(size_t)l16 * 512 + ks * 32 + q4 * 8]);
    bf16x8 a0 = ld8(&P[l16][ks * 32 + q4 * 8]);
    bf16x8 a1 = ld8(&P[16 + l16][ks * 32 + q4 * 8]);
    o[0] = MFMA16(a0, bv8, o[0]);
    o[1] = MFMA16(a1, bv8, o[1]);
  }
  bf16* cb = ctx + ((size_t)b * 512 + m0) * 512 + hh * 64 + w * 16;
#pragma unroll
  for (int rt = 0; rt < 2; rt++)
#pragma unroll
    for (int r = 0; r < 4; r++) {
      int srow = rt * 16 + q4 * 4 + r;
      cb[(size_t)srow * 512 + l16] = f2b(o[rt][r]);
    }
}

// ---------------------------------------------------------------- out proj + residual (fp32 out)
__global__ __launch_bounds__(256) void gemm_out(
    const bf16* __restrict__ ctx, const bf16* __restrict__ WT,
    const float* __restrict__ bd, const float* __restrict__ x, float* __restrict__ out) {
  __shared__ __align__(16) bf16 As[128][40];
  __shared__ __align__(16) bf16 Bs[128][40];
  int tid = threadIdx.x;
  int w = tid >> 6, lane = tid & 63, q4 = lane >> 4, l16 = lane & 15;
  int wr = w >> 1, wc = w & 1;
  int m0 = blockIdx.x * 128, n0 = blockIdx.y * 128;
  f32x4 acc[4][4];
#pragma unroll
  for (int i = 0; i < 4; i++)
#pragma unroll
    for (int j = 0; j < 4; j++) acc[i][j] = (f32x4){0.f, 0.f, 0.f, 0.f};

  for (int kc = 0; kc < 16; kc++) {
    int k0 = kc * 32;
#pragma unroll
    for (int u = tid; u < 512; u += 256) {
      int row = u >> 2, c8 = (u & 3) * 8;
      *(bf16x8*)&As[row][c8] = ld8(&ctx[(size_t)(m0 + row) * 512 + k0 + c8]);
      *(bf16x8*)&Bs[row][c8] = ld8(&WT[(size_t)(n0 + row) * 512 + k0 + c8]);
    }
    __syncthreads();
    bf16x8 af[4], bfr[4];
#pragma unroll
    for (int rt = 0; rt < 4; rt++) af[rt] = ld8(&As[wr * 64 + rt * 16 + l16][q4 * 8]);
#pragma unroll
    for (int nt = 0; nt < 4; nt++) bfr[nt] = ld8(&Bs[wc * 64 + nt * 16 + l16][q4 * 8]);
#pragma unroll
    for (int rt = 0; rt < 4; rt++)
#pragma unroll
      for (int nt = 0; nt < 4; nt++) acc[rt][nt] = MFMA16(af[rt], bfr[nt], acc[rt][nt]);
    __syncthreads();
  }
#pragma unroll
  for (int rt = 0; rt < 4; rt++) {
    int mbase = m0 + wr * 64 + rt * 16 + q4 * 4;
#pragma unroll
    for (int nt = 0; nt < 4; nt++) {
      int n = n0 + wc * 64 + nt * 16 + l16;
      float bsv = bd[n];
#pragma unroll
      for (int r = 0; r < 4; r++) {
        size_t idx = (size_t)(mbase + r) * 512 + n;
        out[idx] = acc[rt][nt][r] + bsv + x[idx];
      }
    }
  }
}

// ---------------------------------------------------------------- launch
extern "C" void kernel_launch(void* const* d_in, const int* in_sizes, int n_in,
                              void* d_out, int out_size, void* d_ws, size_t ws_size,
                              hipStream_t stream) {
  const float* x = (const float*)d_in[0];
  const int* mask = (const int*)d_in[1];
  const float* ln_g = (const float*)d_in[2];
  const float* ln_b = (const float*)d_in[3];
  const float* lna_g = (const float*)d_in[4];
  const float* lna_b = (const float*)d_in[5];
  const float* Wq = (const float*)d_in[6];
  const float* bq = (const float*)d_in[7];
  const float* Wk = (const float*)d_in[8];
  const float* bk = (const float*)d_in[9];
  const float* Wv = (const float*)d_in[10];
  const float* bv = (const float*)d_in[11];
  const float* Wd = (const float*)d_in[12];
  const float* bd = (const float*)d_in[13];

  char* ws = (char*)d_ws;
  const size_t MB = 1024 * 1024;
  if (ws_size < 44 * MB) return;  // need 42 MB of scratch
  bf16* h = (bf16*)(ws);                 // 8 MB  [8192,512]
  bf16* qd = (bf16*)(ws + 8 * MB);       // 8 MB  [B,H,S,DH]
  bf16* kd = (bf16*)(ws + 16 * MB);      // 8 MB  [B,H,S,DH]
  bf16* vTd = (bf16*)(ws + 24 * MB);     // 8 MB  [B,H,DH,S]
  bf16* ctx = (bf16*)(ws + 32 * MB);     // 8 MB  [B,S,D] bf16
  bf16* WqT = (bf16*)(ws + 40 * MB);
  bf16* WkT = (bf16*)(ws + 40 * MB + 512 * 1024);
  bf16* WvT = (bf16*)(ws + 40 * MB + 1024 * 1024);
  bf16* WdT = (bf16*)(ws + 40 * MB + 1536 * 1024);

  transpose512<<<dim3(16, 16, 4), dim3(32, 8), 0, stream>>>(Wq, Wk, Wv, Wd, WqT, WkT, WvT, WdT);
  ln_rows<<<8192, 256, 0, stream>>>(x, ln_g, ln_b, h);
  gemm_qkv<<<dim3(64, 4, 3), 256, 0, stream>>>(h, WqT, WkT, WvT, bq, bk, bv, qd, kd, vTd);
  attn_fused<<<dim3(16, 128), 256, 0, stream>>>(qd, kd, vTd, mask, lna_g, lna_b, ctx);
  gemm_out<<<dim3(64, 4), 256, 0, stream>>>(ctx, WdT, bd, x, (float*)d_out);
}

// Round 3
// 220.173 us; speedup vs baseline: 1.1601x; 1.1601x over previous
//
#include <hip/hip_runtime.h>
#include <hip/hip_bf16.h>
#include <stdint.h>

// B=16, S=512, D=512, H=8, DH=64. Float tensors fp32; mask int32; out fp32.
// Internals: bf16 MFMA operands, fp32 accumulation.

typedef __hip_bfloat16 bf16;
typedef __bf16 bf16x8 __attribute__((ext_vector_type(8)));
typedef float f32x4 __attribute__((ext_vector_type(4)));

#define MFMA16(a, b, c) __builtin_amdgcn_mfma_f32_16x16x32_bf16((a), (b), (c), 0, 0, 0)

static __device__ __forceinline__ bf16 f2b(float v) { return __float2bfloat16(v); }
static __device__ __forceinline__ bf16x8 ld8(const bf16* p) { return *(const bf16x8*)p; }

// ---------------------------------------------------------------- transpose + cast
__global__ __launch_bounds__(256) void transpose512(
    const float* __restrict__ W0, const float* __restrict__ W1,
    const float* __restrict__ W2, const float* __restrict__ W3,
    bf16* __restrict__ T0, bf16* __restrict__ T1,
    bf16* __restrict__ T2, bf16* __restrict__ T3) {
  __shared__ float t[32][33];
  const float* src; bf16* dst;
  switch (blockIdx.z) {
    case 0: src = W0; dst = T0; break;
    case 1: src = W1; dst = T1; break;
    case 2: src = W2; dst = T2; break;
    default: src = W3; dst = T3; break;
  }
  int tx = threadIdx.x, ty = threadIdx.y;  // 32 x 8
  int n0 = blockIdx.x * 32, k0 = blockIdx.y * 32;
#pragma unroll
  for (int i = 0; i < 4; i++) {
    int kk = ty * 4 + i;
    t[kk][tx] = src[(k0 + kk) * 512 + n0 + tx];
  }
  __syncthreads();
#pragma unroll
  for (int i = 0; i < 4; i++) {
    int nn = ty * 4 + i;
    dst[(n0 + nn) * 512 + k0 + tx] = f2b(t[tx][nn]);
  }
}

// ---------------------------------------------------------------- mask -> bitmask
// bits[e/32] bit (e%32) = (mask[e] != 0). One wave covers 64 consecutive elements.
__global__ __launch_bounds__(256) void mask_pack(const int* __restrict__ mask,
                                                 uint32_t* __restrict__ bits) {
  size_t t = (size_t)blockIdx.x * 256 + threadIdx.x;
  int mv = mask[t];
  unsigned long long bal = __ballot(mv != 0);
  if ((threadIdx.x & 63) == 0) {
    ((unsigned long long*)bits)[t >> 6] = bal;
  }
}

// ---------------------------------------------------------------- LayerNorm(x) -> h (bf16)
__global__ __launch_bounds__(256) void ln_rows(
    const float* __restrict__ x, const float* __restrict__ g,
    const float* __restrict__ be, bf16* __restrict__ h) {
  int row = blockIdx.x;
  int tid = threadIdx.x;
  const float* xr = x + (size_t)row * 512;
  float v0 = xr[tid], v1 = xr[tid + 256];
  float s = v0 + v1, s2 = v0 * v0 + v1 * v1;
#pragma unroll
  for (int m = 1; m < 64; m <<= 1) {
    s += __shfl_xor(s, m);
    s2 += __shfl_xor(s2, m);
  }
  __shared__ float rs[4], rs2[4];
  int w = tid >> 6;
  if ((tid & 63) == 0) { rs[w] = s; rs2[w] = s2; }
  __syncthreads();
  s = rs[0] + rs[1] + rs[2] + rs[3];
  s2 = rs2[0] + rs2[1] + rs2[2] + rs2[3];
  float mean = s * (1.0f / 512.0f);
  float var = s2 * (1.0f / 512.0f) - mean * mean;
  float rstd = rsqrtf(var + 1e-5f);
  bf16* hr = h + (size_t)row * 512;
  hr[tid] = f2b((v0 - mean) * rstd * g[tid] + be[tid]);
  hr[tid + 256] = f2b((v1 - mean) * rstd * g[tid + 256] + be[tid + 256]);
}

// ---------------------------------------------------------------- QKV GEMM (unchanged)
__global__ __launch_bounds__(256) void gemm_qkv(
    const bf16* __restrict__ hm,
    const bf16* __restrict__ WT0, const bf16* __restrict__ WT1, const bf16* __restrict__ WT2,
    const float* __restrict__ bq, const float* __restrict__ bk, const float* __restrict__ bv,
    bf16* __restrict__ outq, bf16* __restrict__ outk, bf16* __restrict__ outvT) {
  const int sel = blockIdx.z;
  const bf16* WT = sel == 0 ? WT0 : (sel == 1 ? WT1 : WT2);
  const float* bias = sel == 0 ? bq : (sel == 1 ? bk : bv);
  __shared__ __align__(16) bf16 As[128][40];
  __shared__ __align__(16) bf16 Bs[128][40];
  int tid = threadIdx.x;
  int w = tid >> 6, lane = tid & 63, q4 = lane >> 4, l16 = lane & 15;
  int wr = w >> 1, wc = w & 1;
  int m0 = blockIdx.x * 128, n0 = blockIdx.y * 128;
  f32x4 acc[4][4];
#pragma unroll
  for (int i = 0; i < 4; i++)
#pragma unroll
    for (int j = 0; j < 4; j++) acc[i][j] = (f32x4){0.f, 0.f, 0.f, 0.f};

  for (int kc = 0; kc < 16; kc++) {
    int k0 = kc * 32;
#pragma unroll
    for (int u = tid; u < 512; u += 256) {
      int row = u >> 2, c8 = (u & 3) * 8;
      *(bf16x8*)&As[row][c8] = ld8(&hm[(size_t)(m0 + row) * 512 + k0 + c8]);
      *(bf16x8*)&Bs[row][c8] = ld8(&WT[(size_t)(n0 + row) * 512 + k0 + c8]);
    }
    __syncthreads();
    bf16x8 af[4], bfr[4];
#pragma unroll
    for (int rt = 0; rt < 4; rt++) af[rt] = ld8(&As[wr * 64 + rt * 16 + l16][q4 * 8]);
#pragma unroll
    for (int nt = 0; nt < 4; nt++) bfr[nt] = ld8(&Bs[wc * 64 + nt * 16 + l16][q4 * 8]);
#pragma unroll
    for (int rt = 0; rt < 4; rt++)
#pragma unroll
      for (int nt = 0; nt < 4; nt++) acc[rt][nt] = MFMA16(af[rt], bfr[nt], acc[rt][nt]);
    __syncthreads();
  }

#pragma unroll
  for (int rt = 0; rt < 4; rt++) {
    int mbase = m0 + wr * 64 + rt * 16 + q4 * 4;
    int b = mbase >> 9, s0 = mbase & 511;
#pragma unroll
    for (int nt = 0; nt < 4; nt++) {
      int n = n0 + wc * 64 + nt * 16 + l16;
      float bsv = bias[n];
      int hh = n >> 6, dh = n & 63;
      if (sel == 2) {
        union { bf16 q[4]; uint2 u; } pk;
#pragma unroll
        for (int r = 0; r < 4; r++) pk.q[r] = f2b(acc[rt][nt][r] + bsv);
        *(uint2*)(outvT + ((size_t)((b * 8 + hh) * 64 + dh)) * 512 + s0) = pk.u;
      } else {
        bf16* dst = sel == 0 ? outq : outk;
        float scale = sel == 0 ? 0.125f : 1.0f;
#pragma unroll
        for (int r = 0; r < 4; r++)
          dst[((size_t)((b * 8 + hh) * 512 + s0 + r)) * 64 + dh] =
              f2b((acc[rt][nt][r] + bsv) * scale);
      }
    }
  }
}

// ---------------------------------------------------------------- fused attention, wave-autonomous
// Block = 128 threads (2 waves), 32 q-rows. Wave w owns rows [w*16, w*16+16) x all 512 keys:
// score LN + softmax are wave-local (no cross-wave reductions, no max pass).
__global__ __launch_bounds__(128, 2) void attn_fused(
    const bf16* __restrict__ q, const bf16* __restrict__ k, const bf16* __restrict__ vT,
    const uint32_t* __restrict__ bits, const float* __restrict__ lg,
    const float* __restrict__ lb, bf16* __restrict__ ctx) {
  const int m0 = blockIdx.x * 32;
  const int bh = blockIdx.y;
  const int b = bh >> 3, hh = bh & 7;
  const int tid = threadIdx.x;
  const int w = tid >> 6, lane = tid & 63, q4 = lane >> 4, l16 = lane & 15;

  __shared__ __align__(16) bf16 P[32][520];
  __shared__ uint32_t sbits[32][16];

  // stage mask bits for this block's 32 rows (512 dwords, coalesced uint4)
  {
    const uint32_t* gb = bits + ((size_t)b * 512 + m0) * 16;
    ((uint4*)sbits)[tid] = ((const uint4*)gb)[tid];
  }
  __syncthreads();

  // ---- phase 1: wave-local scores = (q*0.125) @ k^T  (16 rows x 512 keys)
  const bf16* qb = q + ((size_t)bh * 512 + m0 + w * 16) * 64;
  const bf16* kb = k + (size_t)bh * 512 * 64;
  bf16x8 aq0 = ld8(qb + (size_t)l16 * 64 + q4 * 8);
  bf16x8 aq1 = ld8(qb + (size_t)l16 * 64 + 32 + q4 * 8);

  f32x4 acc[32];
#pragma unroll
  for (int nt = 0; nt < 32; nt++) acc[nt] = (f32x4){0.f, 0.f, 0.f, 0.f};
#pragma unroll
  for (int nt = 0; nt < 32; nt++) {
    const bf16* kp = kb + (size_t)(nt * 16 + l16) * 64;
    bf16x8 b0 = ld8(kp + q4 * 8);
    bf16x8 b1 = ld8(kp + 32 + q4 * 8);
    acc[nt] = MFMA16(aq0, b0, acc[nt]);
    acc[nt] = MFMA16(aq1, b1, acc[nt]);
  }

  // ---- phase 2a: per-row mean/var (wave-local; rows r -> q4*4+r within wave tile)
  float mean[4], rstd[4];
#pragma unroll
  for (int r = 0; r < 4; r++) {
    float s = 0.f, s2 = 0.f;
#pragma unroll
    for (int nt = 0; nt < 32; nt++) {
      float v = acc[nt][r];
      s += v;
      s2 += v * v;
    }
#pragma unroll
    for (int mm = 1; mm < 16; mm <<= 1) {
      s += __shfl_xor(s, mm);
      s2 += __shfl_xor(s2, mm);
    }
    float mu = s * (1.0f / 512.0f);
    float var = s2 * (1.0f / 512.0f) - mu * mu;
    mean[r] = mu;
    rstd[r] = rsqrtf(var + 1e-5f);
  }

  // ---- phase 2b: LN + mask + exp + row-sum (no max subtraction: post-LN scores are O(1))
  float se[4] = {0.f, 0.f, 0.f, 0.f};
#pragma unroll
  for (int nt2 = 0; nt2 < 16; nt2++) {
    int col0 = nt2 * 32 + l16;          // nt = 2*nt2
    float g0 = lg[col0], b0 = lb[col0];
    float g1 = lg[col0 + 16], b1 = lb[col0 + 16];
#pragma unroll
    for (int r = 0; r < 4; r++) {
      uint32_t dw = sbits[w * 16 + q4 * 4 + r][nt2];
      float v0 = (acc[2 * nt2][r] - mean[r]) * rstd[r] * g0 + b0;
      float v1 = (acc[2 * nt2 + 1][r] - mean[r]) * rstd[r] * g1 + b1;
      v0 = ((dw >> l16) & 1u) ? v0 : -1.0e9f;
      v1 = ((dw >> (l16 + 16)) & 1u) ? v1 : -1.0e9f;
      float p0 = __expf(v0);
      float p1 = __expf(v1);
      acc[2 * nt2][r] = p0;
      acc[2 * nt2 + 1][r] = p1;
      se[r] += p0 + p1;
    }
  }
  float inv[4];
#pragma unroll
  for (int r = 0; r < 4; r++) {
    float s = se[r];
#pragma unroll
    for (int mm = 1; mm < 16; mm <<= 1) s += __shfl_xor(s, mm);
    inv[r] = 1.0f / s;
  }

  // ---- write normalized probs to LDS (A-operand layout source)
#pragma unroll
  for (int nt = 0; nt < 32; nt++)
#pragma unroll
    for (int r = 0; r < 4; r++)
      P[w * 16 + q4 * 4 + r][nt * 16 + l16] = f2b(acc[nt][r] * inv[r]);
  __syncthreads();

  // ---- phase 3: out = P @ v ; wave w handles dh in [w*32, w*32+32)
  const bf16* vb = vT + ((size_t)bh * 64 + w * 32) * 512;
  f32x4 o[2][2];
#pragma unroll
  for (int rt = 0; rt < 2; rt++)
#pragma unroll
    for (int nt = 0; nt < 2; nt++) o[rt][nt] = (f32x4){0.f, 0.f, 0.f, 0.f};
#pragma unroll
  for (int ks = 0; ks < 16; ks++) {
    bf16x8 b0 = ld8(vb + (size_t)l16 * 512 + ks * 32 + q4 * 8);
    bf16x8 b1 = ld8(vb + (size_t)(16 + l16) * 512 + ks * 32 + q4 * 8);
    bf16x8 a0 = ld8(&P[l16][ks * 32 + q4 * 8]);
    bf16x8 a1 = ld8(&P[16 + l16][ks * 32 + q4 * 8]);
    o[0][0] = MFMA16(a0, b0, o[0][0]);
    o[0][1] = MFMA16(a0, b1, o[0][1]);
    o[1][0] = MFMA16(a1, b0, o[1][0]);
    o[1][1] = MFMA16(a1, b1, o[1][1]);
  }
  // C layout: row = rt*16 + q4*4 + r ; col(dh) = w*32 + nt*16 + l16
#pragma unroll
  for (int rt = 0; rt < 2; rt++)
#pragma unroll
    for (int nt = 0; nt < 2; nt++)
#pragma unroll
      for (int r = 0; r < 4; r++) {
        int row = m0 + rt * 16 + q4 * 4 + r;
        ctx[((size_t)b * 512 + row) * 512 + hh * 64 + w * 32 + nt * 16 + l16] =
            f2b(o[rt][nt][r]);
      }
}

// ---------------------------------------------------------------- out proj + residual (fp32 out)
__global__ __launch_bounds__(256) void gemm_out(
    const bf16* __restrict__ ctx, const bf16* __restrict__ WT,
    const float* __restrict__ bd, const float* __restrict__ x, float* __restrict__ out) {
  __shared__ __align__(16) bf16 As[128][40];
  __shared__ __align__(16) bf16 Bs[128][40];
  int tid = threadIdx.x;
  int w = tid >> 6, lane = tid & 63, q4 = lane >> 4, l16 = lane & 15;
  int wr = w >> 1, wc = w & 1;
  int m0 = blockIdx.x * 128, n0 = blockIdx.y * 128;
  f32x4 acc[4][4];
#pragma unroll
  for (int i = 0; i < 4; i++)
#pragma unroll
    for (int j = 0; j < 4; j++) acc[i][j] = (f32x4){0.f, 0.f, 0.f, 0.f};

  for (int kc = 0; kc < 16; kc++) {
    int k0 = kc * 32;
#pragma unroll
    for (int u = tid; u < 512; u += 256) {
      int row = u >> 2, c8 = (u & 3) * 8;
      *(bf16x8*)&As[row][c8] = ld8(&ctx[(size_t)(m0 + row) * 512 + k0 + c8]);
      *(bf16x8*)&Bs[row][c8] = ld8(&WT[(size_t)(n0 + row) * 512 + k0 + c8]);
    }
    __syncthreads();
    bf16x8 af[4], bfr[4];
#pragma unroll
    for (int rt = 0; rt < 4; rt++) af[rt] = ld8(&As[wr * 64 + rt * 16 + l16][q4 * 8]);
#pragma unroll
    for (int nt = 0; nt < 4; nt++) bfr[nt] = ld8(&Bs[wc * 64 + nt * 16 + l16][q4 * 8]);
#pragma unroll
    for (int rt = 0; rt < 4; rt++)
#pragma unroll
      for (int nt = 0; nt < 4; nt++) acc[rt][nt] = MFMA16(af[rt], bfr[nt], acc[rt][nt]);
    __syncthreads();
  }
#pragma unroll
  for (int rt = 0; rt < 4; rt++) {
    int mbase = m0 + wr * 64 + rt * 16 + q4 * 4;
#pragma unroll
    for (int nt = 0; nt < 4; nt++) {
      int n = n0 + wc * 64 + nt * 16 + l16;
      float bsv = bd[n];
#pragma unroll
      for (int r = 0; r < 4; r++) {
        size_t idx = (size_t)(mbase + r) * 512 + n;
        out[idx] = acc[rt][nt][r] + bsv + x[idx];
      }
    }
  }
}

// ---------------------------------------------------------------- launch
extern "C" void kernel_launch(void* const* d_in, const int* in_sizes, int n_in,
                              void* d_out, int out_size, void* d_ws, size_t ws_size,
                              hipStream_t stream) {
  const float* x = (const float*)d_in[0];
  const int* mask = (const int*)d_in[1];
  const float* ln_g = (const float*)d_in[2];
  const float* ln_b = (const float*)d_in[3];
  const float* lna_g = (const float*)d_in[4];
  const float* lna_b = (const float*)d_in[5];
  const float* Wq = (const float*)d_in[6];
  const float* bq = (const float*)d_in[7];
  const float* Wk = (const float*)d_in[8];
  const float* bk = (const float*)d_in[9];
  const float* Wv = (const float*)d_in[10];
  const float* bv = (const float*)d_in[11];
  const float* Wd = (const float*)d_in[12];
  const float* bd = (const float*)d_in[13];

  char* ws = (char*)d_ws;
  const size_t MB = 1024 * 1024;
  if (ws_size < 44 * MB) return;
  bf16* h = (bf16*)(ws);                 // 8 MB  [8192,512]
  bf16* qd = (bf16*)(ws + 8 * MB);       // 8 MB  [B,H,S,DH]
  bf16* kd = (bf16*)(ws + 16 * MB);      // 8 MB  [B,H,S,DH]
  bf16* vTd = (bf16*)(ws + 24 * MB);     // 8 MB  [B,H,DH,S]
  bf16* ctx = (bf16*)(ws + 32 * MB);     // 8 MB  [B,S,D] bf16
  bf16* WqT = (bf16*)(ws + 40 * MB);
  bf16* WkT = (bf16*)(ws + 40 * MB + 512 * 1024);
  bf16* WvT = (bf16*)(ws + 40 * MB + 1024 * 1024);
  bf16* WdT = (bf16*)(ws + 40 * MB + 1536 * 1024);
  uint32_t* bits = (uint32_t*)(ws + 42 * MB);  // 512 KB

  transpose512<<<dim3(16, 16, 4), dim3(32, 8), 0, stream>>>(Wq, Wk, Wv, Wd, WqT, WkT, WvT, WdT);
  mask_pack<<<16384, 256, 0, stream>>>(mask, bits);
  ln_rows<<<8192, 256, 0, stream>>>(x, ln_g, ln_b, h);
  gemm_qkv<<<dim3(64, 4, 3), 256, 0, stream>>>(h, WqT, WkT, WvT, bq, bk, bv, qd, kd, vTd);
  attn_fused<<<dim3(16, 128), 128, 0, stream>>>(qd, kd, vTd, bits, lna_g, lna_b, ctx);
  gemm_out<<<dim3(64, 4), 256, 0, stream>>>(ctx, WdT, bd, x, (float*)d_out);
}

// Round 4
// 218.542 us; speedup vs baseline: 1.1688x; 1.0075x over previous
//
#include <hip/hip_runtime.h>
#include <hip/hip_bf16.h>
#include <stdint.h>

// B=16, S=512, D=512, H=8, DH=64. Float tensors fp32; mask int32; out fp32.
// Internals: bf16 MFMA operands, fp32 accumulation.

typedef __hip_bfloat16 bf16;
typedef __bf16 bf16x8 __attribute__((ext_vector_type(8)));
typedef float f32x4 __attribute__((ext_vector_type(4)));

#define MFMA16(a, b, c) __builtin_amdgcn_mfma_f32_16x16x32_bf16((a), (b), (c), 0, 0, 0)

static __device__ __forceinline__ bf16 f2b(float v) { return __float2bfloat16(v); }
static __device__ __forceinline__ bf16x8 ld8(const bf16* p) { return *(const bf16x8*)p; }
static __device__ __forceinline__ uint16_t f2bu(float v) {
  return __hip_bfloat16_raw(__float2bfloat16(v)).x;
}
static __device__ __forceinline__ float bu2f(uint32_t u) {
  union { uint32_t i; float f; } c;
  c.i = u << 16;
  return c.f;
}

// ---------------------------------------------------------------- transpose + cast
__global__ __launch_bounds__(256) void transpose512(
    const float* __restrict__ W0, const float* __restrict__ W1,
    const float* __restrict__ W2, const float* __restrict__ W3,
    bf16* __restrict__ T0, bf16* __restrict__ T1,
    bf16* __restrict__ T2, bf16* __restrict__ T3) {
  __shared__ float t[32][33];
  const float* src; bf16* dst;
  switch (blockIdx.z) {
    case 0: src = W0; dst = T0; break;
    case 1: src = W1; dst = T1; break;
    case 2: src = W2; dst = T2; break;
    default: src = W3; dst = T3; break;
  }
  int tx = threadIdx.x, ty = threadIdx.y;  // 32 x 8
  int n0 = blockIdx.x * 32, k0 = blockIdx.y * 32;
#pragma unroll
  for (int i = 0; i < 4; i++) {
    int kk = ty * 4 + i;
    t[kk][tx] = src[(k0 + kk) * 512 + n0 + tx];
  }
  __syncthreads();
#pragma unroll
  for (int i = 0; i < 4; i++) {
    int nn = ty * 4 + i;
    dst[(n0 + nn) * 512 + k0 + tx] = f2b(t[tx][nn]);
  }
}

// ---------------------------------------------------------------- mask -> bitmask
__global__ __launch_bounds__(256) void mask_pack(const int* __restrict__ mask,
                                                 uint32_t* __restrict__ bits) {
  size_t t = (size_t)blockIdx.x * 256 + threadIdx.x;
  int mv = mask[t];
  unsigned long long bal = __ballot(mv != 0);
  if ((threadIdx.x & 63) == 0) {
    ((unsigned long long*)bits)[t >> 6] = bal;
  }
}

// ---------------------------------------------------------------- LayerNorm(x) -> h (bf16)
__global__ __launch_bounds__(256) void ln_rows(
    const float* __restrict__ x, const float* __restrict__ g,
    const float* __restrict__ be, bf16* __restrict__ h) {
  int row = blockIdx.x;
  int tid = threadIdx.x;
  const float* xr = x + (size_t)row * 512;
  float v0 = xr[tid], v1 = xr[tid + 256];
  float s = v0 + v1, s2 = v0 * v0 + v1 * v1;
#pragma unroll
  for (int m = 1; m < 64; m <<= 1) {
    s += __shfl_xor(s, m);
    s2 += __shfl_xor(s2, m);
  }
  __shared__ float rs[4], rs2[4];
  int w = tid >> 6;
  if ((tid & 63) == 0) { rs[w] = s; rs2[w] = s2; }
  __syncthreads();
  s = rs[0] + rs[1] + rs[2] + rs[3];
  s2 = rs2[0] + rs2[1] + rs2[2] + rs2[3];
  float mean = s * (1.0f / 512.0f);
  float var = s2 * (1.0f / 512.0f) - mean * mean;
  float rstd = rsqrtf(var + 1e-5f);
  bf16* hr = h + (size_t)row * 512;
  hr[tid] = f2b((v0 - mean) * rstd * g[tid] + be[tid]);
  hr[tid + 256] = f2b((v1 - mean) * rstd * g[tid + 256] + be[tid + 256]);
}

// ---------------------------------------------------------------- QKV GEMM (unchanged)
__global__ __launch_bounds__(256) void gemm_qkv(
    const bf16* __restrict__ hm,
    const bf16* __restrict__ WT0, const bf16* __restrict__ WT1, const bf16* __restrict__ WT2,
    const float* __restrict__ bq, const float* __restrict__ bk, const float* __restrict__ bv,
    bf16* __restrict__ outq, bf16* __restrict__ outk, bf16* __restrict__ outvT) {
  const int sel = blockIdx.z;
  const bf16* WT = sel == 0 ? WT0 : (sel == 1 ? WT1 : WT2);
  const float* bias = sel == 0 ? bq : (sel == 1 ? bk : bv);
  __shared__ __align__(16) bf16 As[128][40];
  __shared__ __align__(16) bf16 Bs[128][40];
  int tid = threadIdx.x;
  int w = tid >> 6, lane = tid & 63, q4 = lane >> 4, l16 = lane & 15;
  int wr = w >> 1, wc = w & 1;
  int m0 = blockIdx.x * 128, n0 = blockIdx.y * 128;
  f32x4 acc[4][4];
#pragma unroll
  for (int i = 0; i < 4; i++)
#pragma unroll
    for (int j = 0; j < 4; j++) acc[i][j] = (f32x4){0.f, 0.f, 0.f, 0.f};

  for (int kc = 0; kc < 16; kc++) {
    int k0 = kc * 32;
#pragma unroll
    for (int u = tid; u < 512; u += 256) {
      int row = u >> 2, c8 = (u & 3) * 8;
      *(bf16x8*)&As[row][c8] = ld8(&hm[(size_t)(m0 + row) * 512 + k0 + c8]);
      *(bf16x8*)&Bs[row][c8] = ld8(&WT[(size_t)(n0 + row) * 512 + k0 + c8]);
    }
    __syncthreads();
    bf16x8 af[4], bfr[4];
#pragma unroll
    for (int rt = 0; rt < 4; rt++) af[rt] = ld8(&As[wr * 64 + rt * 16 + l16][q4 * 8]);
#pragma unroll
    for (int nt = 0; nt < 4; nt++) bfr[nt] = ld8(&Bs[wc * 64 + nt * 16 + l16][q4 * 8]);
#pragma unroll
    for (int rt = 0; rt < 4; rt++)
#pragma unroll
      for (int nt = 0; nt < 4; nt++) acc[rt][nt] = MFMA16(af[rt], bfr[nt], acc[rt][nt]);
    __syncthreads();
  }

#pragma unroll
  for (int rt = 0; rt < 4; rt++) {
    int mbase = m0 + wr * 64 + rt * 16 + q4 * 4;
    int b = mbase >> 9, s0 = mbase & 511;
#pragma unroll
    for (int nt = 0; nt < 4; nt++) {
      int n = n0 + wc * 64 + nt * 16 + l16;
      float bsv = bias[n];
      int hh = n >> 6, dh = n & 63;
      if (sel == 2) {
        union { bf16 q[4]; uint2 u; } pk;
#pragma unroll
        for (int r = 0; r < 4; r++) pk.q[r] = f2b(acc[rt][nt][r] + bsv);
        *(uint2*)(outvT + ((size_t)((b * 8 + hh) * 64 + dh)) * 512 + s0) = pk.u;
      } else {
        bf16* dst = sel == 0 ? outq : outk;
        float scale = sel == 0 ? 0.125f : 1.0f;
#pragma unroll
        for (int r = 0; r < 4; r++)
          dst[((size_t)((b * 8 + hh) * 512 + s0 + r)) * 64 + dh] =
              f2b((acc[rt][nt][r] + bsv) * scale);
      }
    }
  }
}

// ---------------------------------------------------------------- fused attention v3
// One wave per block (64 thr), 16 q-rows, all 512 keys. Zero barriers.
// Scores streamed to LDS (ST[key][row] bf16) to kill register pressure;
// LN+mask+exp in-place; softmax normalization folded into output scale.
// XCD swizzle: all 32 m-tiles of one bh stay on one XCD (k/v L2-resident).
__global__ __launch_bounds__(64, 4) void attn_fused(
    const bf16* __restrict__ q, const bf16* __restrict__ k, const bf16* __restrict__ vT,
    const uint32_t* __restrict__ bits, const float* __restrict__ lg,
    const float* __restrict__ lb, bf16* __restrict__ ctx) {
  const int id = blockIdx.x;             // 0..4095
  const int xcd = id & 7;
  const int j = id >> 3;                 // 0..511
  const int mt = j & 31;
  const int bh = ((j >> 5) << 3) | xcd;  // 0..127 ; bh%8 == xcd
  const int m0 = mt * 16;
  const int b = bh >> 3, hh = bh & 7;
  const int lane = threadIdx.x;
  const int q4 = lane >> 4, l16 = lane & 15;

  __shared__ uint16_t ST[512][18];   // scores, then unnormalized probs (bf16 bits)
  __shared__ uint32_t sbits[16][16]; // mask bits: [row][key dword]

  // stage mask bits: 16 rows x 16 dwords = 64 uint4, one per lane
  {
    const uint4* gb = (const uint4*)(bits + ((size_t)b * 512 + m0) * 16);
    uint4 t = gb[lane];
    int rr = lane >> 2, cc = (lane & 3) * 4;
    sbits[rr][cc] = t.x; sbits[rr][cc + 1] = t.y;
    sbits[rr][cc + 2] = t.z; sbits[rr][cc + 3] = t.w;
  }

  // ---- phase 1: scores (16 x 512), streamed to LDS; stats in registers
  const bf16* qb = q + ((size_t)bh * 512 + m0) * 64;
  const bf16* kb = k + (size_t)bh * 512 * 64;
  bf16x8 aq0 = ld8(qb + (size_t)l16 * 64 + q4 * 8);
  bf16x8 aq1 = ld8(qb + (size_t)l16 * 64 + 32 + q4 * 8);

  float s[4] = {0.f, 0.f, 0.f, 0.f}, s2[4] = {0.f, 0.f, 0.f, 0.f};
#pragma unroll
  for (int nt = 0; nt < 32; nt++) {
    const bf16* kp = kb + (size_t)(nt * 16 + l16) * 64;
    bf16x8 b0 = ld8(kp + q4 * 8);
    bf16x8 b1 = ld8(kp + 32 + q4 * 8);
    f32x4 acc = (f32x4){0.f, 0.f, 0.f, 0.f};
    acc = MFMA16(aq0, b0, acc);
    acc = MFMA16(aq1, b1, acc);
    uint32_t d0, d1;
#pragma unroll
    for (int r = 0; r < 2; r++) {
      float v = acc[r];
      s[r] += v; s2[r] += v * v;
    }
#pragma unroll
    for (int r = 2; r < 4; r++) {
      float v = acc[r];
      s[r] += v; s2[r] += v * v;
    }
    d0 = (uint32_t)f2bu(acc[0]) | ((uint32_t)f2bu(acc[1]) << 16);
    d1 = (uint32_t)f2bu(acc[2]) | ((uint32_t)f2bu(acc[3]) << 16);
    *(uint32_t*)&ST[nt * 16 + l16][q4 * 4] = d0;
    *(uint32_t*)&ST[nt * 16 + l16][q4 * 4 + 2] = d1;
  }

  float mean[4], rstd[4];
#pragma unroll
  for (int r = 0; r < 4; r++) {
    float a = s[r], a2 = s2[r];
#pragma unroll
    for (int mm = 1; mm < 16; mm <<= 1) {
      a += __shfl_xor(a, mm);
      a2 += __shfl_xor(a2, mm);
    }
    float mu = a * (1.0f / 512.0f);
    float var = a2 * (1.0f / 512.0f) - mu * mu;
    mean[r] = mu;
    rstd[r] = rsqrtf(var + 1e-5f);
  }

  // ---- phase 2: LN + mask + exp, in place (each lane rewrites its own slots)
  float se[4] = {0.f, 0.f, 0.f, 0.f};
#pragma unroll
  for (int nt2 = 0; nt2 < 16; nt2++) {
    int colA = nt2 * 32 + l16, colB = colA + 16;
    float gA = lg[colA], bA = lb[colA];
    float gB = lg[colB], bB = lb[colB];
    uint32_t dA0 = *(uint32_t*)&ST[colA][q4 * 4];
    uint32_t dA1 = *(uint32_t*)&ST[colA][q4 * 4 + 2];
    uint32_t dB0 = *(uint32_t*)&ST[colB][q4 * 4];
    uint32_t dB1 = *(uint32_t*)&ST[colB][q4 * 4 + 2];
    float vA[4] = {bu2f(dA0 & 0xffff), bu2f(dA0 >> 16), bu2f(dA1 & 0xffff), bu2f(dA1 >> 16)};
    float vB[4] = {bu2f(dB0 & 0xffff), bu2f(dB0 >> 16), bu2f(dB1 & 0xffff), bu2f(dB1 >> 16)};
    uint16_t pA[4], pB[4];
#pragma unroll
    for (int r = 0; r < 4; r++) {
      uint32_t mw = sbits[q4 * 4 + r][nt2];
      float a = (vA[r] - mean[r]) * rstd[r] * gA + bA;
      float c = (vB[r] - mean[r]) * rstd[r] * gB + bB;
      a = ((mw >> l16) & 1u) ? a : -1.0e9f;
      c = ((mw >> (l16 + 16)) & 1u) ? c : -1.0e9f;
      uint16_t pa = f2bu(__expf(a));
      uint16_t pc = f2bu(__expf(c));
      pA[r] = pa; pB[r] = pc;
      se[r] += bu2f(pa) + bu2f(pc);
    }
    *(uint32_t*)&ST[colA][q4 * 4] = (uint32_t)pA[0] | ((uint32_t)pA[1] << 16);
    *(uint32_t*)&ST[colA][q4 * 4 + 2] = (uint32_t)pA[2] | ((uint32_t)pA[3] << 16);
    *(uint32_t*)&ST[colB][q4 * 4] = (uint32_t)pB[0] | ((uint32_t)pB[1] << 16);
    *(uint32_t*)&ST[colB][q4 * 4 + 2] = (uint32_t)pB[2] | ((uint32_t)pB[3] << 16);
  }
  float inv[4];
#pragma unroll
  for (int r = 0; r < 4; r++) {
    float a = se[r];
#pragma unroll
    for (int mm = 1; mm < 16; mm <<= 1) a += __shfl_xor(a, mm);
    inv[r] = 1.0f / a;
  }

  // ---- phase 3: out = P @ v (unnormalized), scale by inv at the end
  const bf16* vb = vT + (size_t)bh * 64 * 512;
  f32x4 o[4];
#pragma unroll
  for (int nt = 0; nt < 4; nt++) o[nt] = (f32x4){0.f, 0.f, 0.f, 0.f};
#pragma unroll
  for (int ks = 0; ks < 16; ks++) {
    union { uint16_t u[8]; bf16x8 v; } af;
#pragma unroll
    for (int jj = 0; jj < 8; jj++) af.u[jj] = ST[ks * 32 + q4 * 8 + jj][l16];
#pragma unroll
    for (int nt = 0; nt < 4; nt++) {
      bf16x8 bv8 = ld8(vb + (size_t)(nt * 16 + l16) * 512 + ks * 32 + q4 * 8);
      o[nt] = MFMA16(af.v, bv8, o[nt]);
    }
  }
  // C layout: row = q4*4 + r ; col(dh) = nt*16 + l16
  bf16* cb = ctx + ((size_t)b * 512 + m0) * 512 + hh * 64;
#pragma unroll
  for (int nt = 0; nt < 4; nt++)
#pragma unroll
    for (int r = 0; r < 4; r++)
      cb[(size_t)(q4 * 4 + r) * 512 + nt * 16 + l16] = f2b(o[nt][r] * inv[r]);
}

// ---------------------------------------------------------------- out proj + residual (fp32 out)
__global__ __launch_bounds__(256) void gemm_out(
    const bf16* __restrict__ ctx, const bf16* __restrict__ WT,
    const float* __restrict__ bd, const float* __restrict__ x, float* __restrict__ out) {
  __shared__ __align__(16) bf16 As[128][40];
  __shared__ __align__(16) bf16 Bs[128][40];
  int tid = threadIdx.x;
  int w = tid >> 6, lane = tid & 63, q4 = lane >> 4, l16 = lane & 15;
  int wr = w >> 1, wc = w & 1;
  int m0 = blockIdx.x * 128, n0 = blockIdx.y * 128;
  f32x4 acc[4][4];
#pragma unroll
  for (int i = 0; i < 4; i++)
#pragma unroll
    for (int j = 0; j < 4; j++) acc[i][j] = (f32x4){0.f, 0.f, 0.f, 0.f};

  for (int kc = 0; kc < 16; kc++) {
    int k0 = kc * 32;
#pragma unroll
    for (int u = tid; u < 512; u += 256) {
      int row = u >> 2, c8 = (u & 3) * 8;
      *(bf16x8*)&As[row][c8] = ld8(&ctx[(size_t)(m0 + row) * 512 + k0 + c8]);
      *(bf16x8*)&Bs[row][c8] = ld8(&WT[(size_t)(n0 + row) * 512 + k0 + c8]);
    }
    __syncthreads();
    bf16x8 af[4], bfr[4];
#pragma unroll
    for (int rt = 0; rt < 4; rt++) af[rt] = ld8(&As[wr * 64 + rt * 16 + l16][q4 * 8]);
#pragma unroll
    for (int nt = 0; nt < 4; nt++) bfr[nt] = ld8(&Bs[wc * 64 + nt * 16 + l16][q4 * 8]);
#pragma unroll
    for (int rt = 0; rt < 4; rt++)
#pragma unroll
      for (int nt = 0; nt < 4; nt++) acc[rt][nt] = MFMA16(af[rt], bfr[nt], acc[rt][nt]);
    __syncthreads();
  }
#pragma unroll
  for (int rt = 0; rt < 4; rt++) {
    int mbase = m0 + wr * 64 + rt * 16 + q4 * 4;
#pragma unroll
    for (int nt = 0; nt < 4; nt++) {
      int n = n0 + wc * 64 + nt * 16 + l16;
      float bsv = bd[n];
#pragma unroll
      for (int r = 0; r < 4; r++) {
        size_t idx = (size_t)(mbase + r) * 512 + n;
        out[idx] = acc[rt][nt][r] + bsv + x[idx];
      }
    }
  }
}

// ---------------------------------------------------------------- launch
extern "C" void kernel_launch(void* const* d_in, const int* in_sizes, int n_in,
                              void* d_out, int out_size, void* d_ws, size_t ws_size,
                              hipStream_t stream) {
  const float* x = (const float*)d_in[0];
  const int* mask = (const int*)d_in[1];
  const float* ln_g = (const float*)d_in[2];
  const float* ln_b = (const float*)d_in[3];
  const float* lna_g = (const float*)d_in[4];
  const float* lna_b = (const float*)d_in[5];
  const float* Wq = (const float*)d_in[6];
  const float* bq = (const float*)d_in[7];
  const float* Wk = (const float*)d_in[8];
  const float* bk = (const float*)d_in[9];
  const float* Wv = (const float*)d_in[10];
  const float* bv = (const float*)d_in[11];
  const float* Wd = (const float*)d_in[12];
  const float* bd = (const float*)d_in[13];

  char* ws = (char*)d_ws;
  const size_t MB = 1024 * 1024;
  if (ws_size < 44 * MB) return;
  bf16* h = (bf16*)(ws);                 // 8 MB  [8192,512]
  bf16* qd = (bf16*)(ws + 8 * MB);       // 8 MB  [B,H,S,DH]
  bf16* kd = (bf16*)(ws + 16 * MB);      // 8 MB  [B,H,S,DH]
  bf16* vTd = (bf16*)(ws + 24 * MB);     // 8 MB  [B,H,DH,S]
  bf16* ctx = (bf16*)(ws + 32 * MB);     // 8 MB  [B,S,D] bf16
  bf16* WqT = (bf16*)(ws + 40 * MB);
  bf16* WkT = (bf16*)(ws + 40 * MB + 512 * 1024);
  bf16* WvT = (bf16*)(ws + 40 * MB + 1024 * 1024);
  bf16* WdT = (bf16*)(ws + 40 * MB + 1536 * 1024);
  uint32_t* bits = (uint32_t*)(ws + 42 * MB);  // 512 KB

  transpose512<<<dim3(16, 16, 4), dim3(32, 8), 0, stream>>>(Wq, Wk, Wv, Wd, WqT, WkT, WvT, WdT);
  mask_pack<<<16384, 256, 0, stream>>>(mask, bits);
  ln_rows<<<8192, 256, 0, stream>>>(x, ln_g, ln_b, h);
  gemm_qkv<<<dim3(64, 4, 3), 256, 0, stream>>>(h, WqT, WkT, WvT, bq, bk, bv, qd, kd, vTd);
  attn_fused<<<4096, 64, 0, stream>>>(qd, kd, vTd, bits, lna_g, lna_b, ctx);
  gemm_out<<<dim3(64, 4), 256, 0, stream>>>(ctx, WdT, bd, x, (float*)d_out);
}